// Round 1
// baseline (302.299 us; speedup 1.0000x reference)
//
#include <hip/hip_runtime.h>

// FMFMNeuron: snntorch Leaky neuron scan.
//   cur[t,b]  = s[t,b,0]*w1 + s[t,b,1]*w2
//   reset     = (mem > 1)
//   mem       = 0.95*mem + cur - reset
//   spk[t,b]  = (mem > 1)
// Memory-bound streaming: 200 MB in + 100 MB out => ~48 us at 6.3 TB/s.
//
// Numerics: outputs are hard thresholds of mem; match numpy's op-by-op fp32
// rounding exactly (no FMA contraction) via __fmul_rn/__fadd_rn/__fsub_rn,
// else borderline trajectories (~few expected out of 25M neuron-steps) flip.

constexpr int T_STEPS = 50;
constexpr int BATCH   = 500000;
constexpr int HALF    = BATCH / 2;   // 2 neurons per thread

__global__ __launch_bounds__(256)
void snn_leaky_kernel(const float4* __restrict__ in4,   // [T][HALF] float4 = 2 neurons' (s0,s1)
                      const float*  __restrict__ W,     // [2]
                      float2*       __restrict__ out2)  // [T][HALF]
{
    const int i = blockIdx.x * blockDim.x + threadIdx.x;
    if (i >= HALF) return;

    const float w1 = W[0];
    const float w2 = W[1];

    float mem0 = 0.0f, mem1 = 0.0f;

    const float4* __restrict__ p = in4 + i;
    float2*       __restrict__ q = out2 + i;

    // Partial unroll: lets the compiler hoist a few independent float4 loads
    // ahead of the dependent mem-chain without blowing VGPRs.
    #pragma unroll 5
    for (int t = 0; t < T_STEPS; ++t) {
        const float4 s = p[(size_t)t * HALF];

        // cur = (s0*w1) + (s1*w2), separately rounded (matches numpy einsum)
        const float cur0 = __fadd_rn(__fmul_rn(s.x, w1), __fmul_rn(s.y, w2));
        const float cur1 = __fadd_rn(__fmul_rn(s.z, w1), __fmul_rn(s.w, w2));

        // reset from PREVIOUS mem; (mem-1>0) == (mem>1) exactly in fp32
        const float r0 = (mem0 > 1.0f) ? 1.0f : 0.0f;
        const float r1 = (mem1 > 1.0f) ? 1.0f : 0.0f;

        // mem = ((0.95*mem) + cur) - reset, separately rounded
        mem0 = __fsub_rn(__fadd_rn(__fmul_rn(0.95f, mem0), cur0), r0);
        mem1 = __fsub_rn(__fadd_rn(__fmul_rn(0.95f, mem1), cur1), r1);

        float2 spk;
        spk.x = (mem0 > 1.0f) ? 1.0f : 0.0f;
        spk.y = (mem1 > 1.0f) ? 1.0f : 0.0f;
        q[(size_t)t * HALF] = spk;
    }
}

extern "C" void kernel_launch(void* const* d_in, const int* in_sizes, int n_in,
                              void* d_out, int out_size, void* d_ws, size_t ws_size,
                              hipStream_t stream) {
    const float4* in4 = (const float4*)d_in[0];   // spike_seq [T,B,2] fp32
    const float*  W   = (const float*)d_in[1];    // [1,2] fp32
    float2*       out = (float2*)d_out;           // spk_rec [T,B,1] fp32

    const int threads = 256;
    const int blocks  = (HALF + threads - 1) / threads;  // 977
    snn_leaky_kernel<<<blocks, threads, 0, stream>>>(in4, W, out);
}